// Round 7
// baseline (18838.885 us; speedup 1.0000x reference)
//
#include <hip/hip_runtime.h>
#include <hip/hip_bf16.h>
#include <math.h>

#define T_STEPS 1024
#define HDIM    2048
#define ADIM    64
#define NBLK    256
#define NTHR    512
#define WPB     (NTHR / 64)   // 8 waves/block -> 2048 waves = one per output row

__device__ __forceinline__ float elu_f(float x)      { return x > 0.f ? x : expm1f(x); }
__device__ __forceinline__ float sigmoid_f(float x)  { return 1.f / (1.f + expf(-x)); }
__device__ __forceinline__ float softplus_f(float x) { return x > 0.f ? x + log1pf(expf(-x)) : log1pf(expf(x)); }

// Device-coherent relaxed 8B atomics. Tag hi32, payload lo32 — one store
// publishes data+readiness atomically; every poll load is simultaneously
// flag AND data (single serialized hop). Six rounds of A/B established the
// protocol optimum is exactly this:
//   R1: separate ready-flags (+1 hop)              -> +27% time
//   R2: 2-deep pipelined polling (2x traffic)      -> +30% time
//   R5: 128B/slot padding (16x lines, 10x fetch)   -> +18% time
//   R6: contiguous 4-slot groups (8-way LDS bank
//       conflict + 4x poll fetch amplification)    -> +58% time
// => single-hop, dense mailbox, stride-512 slot map, immediate checks.
__device__ __forceinline__ unsigned long long cload64(const unsigned long long* p) {
    return __hip_atomic_load(p, __ATOMIC_RELAXED, __HIP_MEMORY_SCOPE_AGENT);
}
__device__ __forceinline__ void cstore64(unsigned long long* p, unsigned long long v) {
    __hip_atomic_store(p, v, __ATOMIC_RELAXED, __HIP_MEMORY_SCOPE_AGENT);
}
__device__ __forceinline__ unsigned long long pack_tag(unsigned tag, float v) {
    return ((unsigned long long)tag << 32) | (unsigned long long)__float_as_uint(v);
}

// Spin until all 2048 tagged slots for `tag` are visible; stash payloads into
// LDS. Thread i owns slots {i, i+512, i+1024, i+1536}: each poll load is a
// dense 512B span per wave (coalescing-optimal, R6 proved the alternative
// costs 58%) and LDS writes are conflict-free. Ends with __syncthreads.
__device__ __forceinline__ void consume_vec(const unsigned long long* __restrict__ tg,
                                            unsigned tag, float* __restrict__ lsv) {
    const int i = threadIdx.x;
    unsigned pend = 0xFu;
    while (pend) {
        #pragma unroll
        for (int q = 0; q < 4; ++q) {
            if (pend & (1u << q)) {
                const unsigned long long x = cload64(tg + i + q * NTHR);
                if ((unsigned)(x >> 32) == tag) {
                    lsv[i + q * NTHR] = __uint_as_float((unsigned)x);
                    pend &= ~(1u << q);
                }
            }
        }
    }
    __syncthreads();
}

// Pin a loaded float4 into VGPRs: the asm makes the value opaque so the
// register allocator cannot rematerialize the load inside the t-loop.
#define KEEP4(v) asm volatile("" : "+v"(v.x), "+v"(v.y), "+v"(v.z), "+v"(v.w))

// ---------------------------------------------------------------------------
// Persistent sequential kernel, now with the head GEMVs fused in.
// Wave j holds 7 weight rows register-resident (3x W_hh, fc1, fc2, mean_w,
// std_w = 224 VGPRs; ~300/512 unified incl. working set). Per stage: poll
// tagged u64s -> LDS (double-buffered), dot vs register weights, wave-reduce,
// lane0 publishes one tagged u64.
// HEAD FUSION: at step t's stage 1 the freshly consumed buffer holds s_{t-1};
// after the stage-1 publish (producer path unblocked) each wave computes
// mean/std dots for row (t-1) and lane0 stores out directly. This ~0.13 us of
// math hides inside the ~2.5 us stage-2 spin -> the whole 440 us head_gemm
// kernel disappears from the critical path. lsv double-buffering (validated
// in R6) makes it race-free: stage-2's consume writes the OTHER buffer.
// ---------------------------------------------------------------------------
__global__ void __launch_bounds__(NTHR, 2) gru_seq_kernel(
    const float* __restrict__ actions, const float* __restrict__ state,
    const float* __restrict__ W_ih, const float* __restrict__ W_hh,
    const float* __restrict__ b_ih, const float* __restrict__ b_hh,
    const float* __restrict__ fc1_w, const float* __restrict__ fc1_b,
    const float* __restrict__ fc2_w, const float* __restrict__ fc2_b,
    const float* __restrict__ mean_w, const float* __restrict__ mean_b,
    const float* __restrict__ std_w,  const float* __restrict__ std_b,
    float* __restrict__ out,
    unsigned long long* __restrict__ tg0,
    unsigned long long* __restrict__ tg1,
    unsigned long long* __restrict__ tg2)
{
    __shared__ float lsv[2][HDIM];
    const int lane = threadIdx.x & 63;
    const int wave = threadIdx.x >> 6;
    const int j    = blockIdx.x * WPB + wave;   // 0..2047

    // --- prologue: weights -> registers ---
    float4 wr[8], wz[8], wn[8], f1[8], f2[8], mw[8], sw[8];
    {
        const float4* p0 = (const float4*)(W_hh + (size_t)j * HDIM);
        const float4* p1 = (const float4*)(W_hh + (size_t)(HDIM + j) * HDIM);
        const float4* p2 = (const float4*)(W_hh + (size_t)(2 * HDIM + j) * HDIM);
        const float4* p3 = (const float4*)(fc1_w + (size_t)j * HDIM);
        const float4* p4 = (const float4*)(fc2_w + (size_t)j * HDIM);
        const float4* p5 = (const float4*)(mean_w + (size_t)j * HDIM);
        const float4* p6 = (const float4*)(std_w + (size_t)j * HDIM);
        #pragma unroll
        for (int i = 0; i < 8; ++i) {
            wr[i] = p0[i * 64 + lane]; KEEP4(wr[i]);
            wz[i] = p1[i * 64 + lane]; KEEP4(wz[i]);
            wn[i] = p2[i * 64 + lane]; KEEP4(wn[i]);
            f1[i] = p3[i * 64 + lane]; KEEP4(f1[i]);
            f2[i] = p4[i * 64 + lane]; KEEP4(f2[i]);
            mw[i] = p5[i * 64 + lane]; KEEP4(mw[i]);
            sw[i] = p6[i * 64 + lane]; KEEP4(sw[i]);
        }
    }
    const float wih_r = W_ih[(size_t)j * ADIM + lane];
    const float wih_z = W_ih[(size_t)(HDIM + j) * ADIM + lane];
    const float wih_n = W_ih[(size_t)(2 * HDIM + j) * ADIM + lane];
    const float bias_r = b_ih[j] + b_hh[j];
    const float bias_z = b_ih[HDIM + j] + b_hh[HDIM + j];
    const float bihn   = b_ih[2 * HDIM + j];
    const float bhhn   = b_hh[2 * HDIM + j];
    const float fb1    = fc1_b[j];
    const float fb2    = fc2_b[j];
    const float mb     = mean_b[j];
    const float sb     = std_b[j];

    int cur = 0;   // lsv buffer most recently filled

    for (int t = 0; t < T_STEPS; ++t) {
        const unsigned base = 3u * (unsigned)t;

        // ================= stage 1: GRU cell =================
        const float av = actions[t * ADIM + lane];   // independent; overlaps the spin
        if (t == 0) {
            #pragma unroll
            for (int q = 0; q < 4; ++q)
                lsv[0][threadIdx.x + q * NTHR] = state[threadIdx.x + q * NTHR];
            cur = 0;
            __syncthreads();
        } else {
            consume_vec(tg2, base, lsv[cur ^ 1]);    // s_{t-1} (tag 3t)
            cur ^= 1;
        }
        {
            const float4* ls4 = (const float4*)lsv[cur];
            float dr = 0.f, dz = 0.f, dnH = 0.f;
            #pragma unroll
            for (int i = 0; i < 8; ++i) {
                const float4 s4 = ls4[i * 64 + lane];
                dr  += s4.x * wr[i].x + s4.y * wr[i].y + s4.z * wr[i].z + s4.w * wr[i].w;
                dz  += s4.x * wz[i].x + s4.y * wz[i].y + s4.z * wz[i].z + s4.w * wz[i].w;
                dnH += s4.x * wn[i].x + s4.y * wn[i].y + s4.z * wn[i].z + s4.w * wn[i].w;
            }
            float dnA = av * wih_n;
            dr += av * wih_r;
            dz += av * wih_z;
            #pragma unroll
            for (int m = 32; m > 0; m >>= 1) {
                dr  += __shfl_xor(dr, m, 64);
                dz  += __shfl_xor(dz, m, 64);
                dnH += __shfl_xor(dnH, m, 64);
                dnA += __shfl_xor(dnA, m, 64);
            }
            if (lane == 0) {
                const float r  = sigmoid_f(dr + bias_r);
                const float z  = sigmoid_f(dz + bias_z);
                const float n  = tanhf(dnA + bihn + r * (dnH + bhhn));
                const float hp = lsv[cur][j];
                const float hn = (1.f - z) * n + z * hp;
                cstore64(&tg0[j], pack_tag(base + 1u, elu_f(hn)));
            }
        }

        // ----- fused head for row t-1 (producer already published; this
        // hides inside the stage-2 spin). Reads lsv[cur] = s_{t-1}; the
        // stage-2 consume below writes lsv[cur^1] — no race. -----
        if (t > 0) {
            const float4* ls4 = (const float4*)lsv[cur];
            float dm = 0.f, ds = 0.f;
            #pragma unroll
            for (int i = 0; i < 8; ++i) {
                const float4 s4 = ls4[i * 64 + lane];
                dm += s4.x * mw[i].x + s4.y * mw[i].y + s4.z * mw[i].z + s4.w * mw[i].w;
                ds += s4.x * sw[i].x + s4.y * sw[i].y + s4.z * sw[i].z + s4.w * sw[i].w;
            }
            #pragma unroll
            for (int m = 32; m > 0; m >>= 1) {
                dm += __shfl_xor(dm, m, 64);
                ds += __shfl_xor(ds, m, 64);
            }
            if (lane == 0) {
                out[(size_t)(t - 1) * HDIM + j] = dm + mb;
                out[(size_t)T_STEPS * HDIM + (size_t)(t - 1) * HDIM + j] = softplus_f(ds + sb);
            }
        }

        // ================= stage 2: fc1 =================
        consume_vec(tg0, base + 1u, lsv[cur ^ 1]);
        cur ^= 1;
        {
            const float4* ls4 = (const float4*)lsv[cur];
            float d1 = 0.f;
            #pragma unroll
            for (int i = 0; i < 8; ++i) {
                const float4 s4 = ls4[i * 64 + lane];
                d1 += s4.x * f1[i].x + s4.y * f1[i].y + s4.z * f1[i].z + s4.w * f1[i].w;
            }
            #pragma unroll
            for (int m = 32; m > 0; m >>= 1) d1 += __shfl_xor(d1, m, 64);
            if (lane == 0) cstore64(&tg1[j], pack_tag(base + 2u, elu_f(d1 + fb1)));
        }

        // ================= stage 3: fc2 -> s_t =================
        consume_vec(tg1, base + 2u, lsv[cur ^ 1]);
        cur ^= 1;
        {
            const float4* ls4 = (const float4*)lsv[cur];
            float d2 = 0.f;
            #pragma unroll
            for (int i = 0; i < 8; ++i) {
                const float4 s4 = ls4[i * 64 + lane];
                d2 += s4.x * f2[i].x + s4.y * f2[i].y + s4.z * f2[i].z + s4.w * f2[i].w;
            }
            #pragma unroll
            for (int m = 32; m > 0; m >>= 1) d2 += __shfl_xor(d2, m, 64);
            if (lane == 0) cstore64(&tg2[j], pack_tag(base + 3u, elu_f(d2 + fb2)));
        }
    }

    // ----- final head row (s_{1023} was published but never consumed) -----
    consume_vec(tg2, 3u * (unsigned)T_STEPS, lsv[cur ^ 1]);
    cur ^= 1;
    {
        const float4* ls4 = (const float4*)lsv[cur];
        float dm = 0.f, ds = 0.f;
        #pragma unroll
        for (int i = 0; i < 8; ++i) {
            const float4 s4 = ls4[i * 64 + lane];
            dm += s4.x * mw[i].x + s4.y * mw[i].y + s4.z * mw[i].z + s4.w * mw[i].w;
            ds += s4.x * sw[i].x + s4.y * sw[i].y + s4.z * sw[i].z + s4.w * sw[i].w;
        }
        #pragma unroll
        for (int m = 32; m > 0; m >>= 1) {
            dm += __shfl_xor(dm, m, 64);
            ds += __shfl_xor(ds, m, 64);
        }
        if (lane == 0) {
            out[(size_t)(T_STEPS - 1) * HDIM + j] = dm + mb;
            out[(size_t)T_STEPS * HDIM + (size_t)(T_STEPS - 1) * HDIM + j] = softplus_f(ds + sb);
        }
    }
}

// ---------------------------------------------------------------------------
extern "C" void kernel_launch(void* const* d_in, const int* in_sizes, int n_in,
                              void* d_out, int out_size, void* d_ws, size_t ws_size,
                              hipStream_t stream) {
    (void)in_sizes; (void)n_in; (void)out_size; (void)ws_size;
    const float* actions = (const float*)d_in[0];
    const float* state   = (const float*)d_in[1];
    const float* W_ih    = (const float*)d_in[2];
    const float* W_hh    = (const float*)d_in[3];
    const float* b_ih    = (const float*)d_in[4];
    const float* b_hh    = (const float*)d_in[5];
    const float* fc1_w   = (const float*)d_in[6];
    const float* fc1_b   = (const float*)d_in[7];
    const float* fc2_w   = (const float*)d_in[8];
    const float* fc2_b   = (const float*)d_in[9];
    const float* mean_w  = (const float*)d_in[10];
    const float* mean_b  = (const float*)d_in[11];
    const float* std_w   = (const float*)d_in[12];
    const float* std_b   = (const float*)d_in[13];
    float* out = (float*)d_out;

    unsigned long long* tg0 = (unsigned long long*)d_ws;      // 16 KB each
    unsigned long long* tg1 = tg0 + HDIM;
    unsigned long long* tg2 = tg1 + HDIM;
    // no memset needed: 0xAA poison never matches a ticket (1..3072), and
    // within a run tags strictly increase while every slot is rewritten
    // each step — cross-run leftovers can never alias a wanted tag early.

    void* args[] = { &actions, &state, &W_ih, &W_hh, &b_ih, &b_hh,
                     &fc1_w, &fc1_b, &fc2_w, &fc2_b,
                     &mean_w, &mean_b, &std_w, &std_b,
                     &out, &tg0, &tg1, &tg2 };
    hipLaunchCooperativeKernel((const void*)gru_seq_kernel,
                               dim3(NBLK), dim3(NTHR), args, 0, stream);
}